// Round 4
// baseline (241.927 us; speedup 1.0000x reference)
//
#include <hip/hip_runtime.h>
#include <hip/hip_fp16.h>

#define NMESH 128
#define NMESH2 (128 * 128)
#define NMESH3 (128 * 128 * 128)
#define NPOINTS 100000
#define NCH 16
#define NBINS 4096        // 16^3 coarse bins (8^3 cells each)

// ---------------- workspace layout (bytes) ----------------
// [0, 64Mi)               meshT   : fp16 (X,Y,Z,C)
// [64Mi, +16K)            counts  : int[4096]
// [64Mi+16K, +16K)        offsets : int[4096]
// [64Mi+32K, +1.6M)       sorted  : float4[100000] = (x,y,z,orig_idx_bits)
#define WS_MESHT_OFF   0
#define WS_COUNTS_OFF  (64u * 1024u * 1024u)
#define WS_OFFSETS_OFF (WS_COUNTS_OFF + 16384u)
#define WS_SORTED_OFF  (WS_OFFSETS_OFF + 16384u)
#define WS_NEEDED      (WS_SORTED_OFF + (size_t)NPOINTS * 16u)

__device__ __forceinline__ void cell_of_point(const float px, const float py,
                                              const float pz, int& rx, int& ry, int& rz) {
    const float SP = 0.1f;
    rx = (int)rintf(px / SP);
    ry = (int)rintf(py / SP);
    rz = (int)rintf(pz / SP);
}

// ---------------------------------------------------------------------------
// Transpose (C,X,Y,Z) fp32 -> (X,Y,Z,C) fp16. BW-floor bound.
// ---------------------------------------------------------------------------
__global__ __launch_bounds__(256) void transpose_to_half_v2(
    const float* __restrict__ in, __half* __restrict__ outT)
{
    const int s = blockIdx.x * 256 + threadIdx.x;

    float v[NCH];
#pragma unroll
    for (int c = 0; c < NCH; ++c)
        v[c] = in[(size_t)c * NMESH3 + s];

    uint32_t u[8];
#pragma unroll
    for (int k = 0; k < 8; ++k) {
        u[k] = (uint32_t)__half_as_ushort(__float2half(v[2 * k])) |
               ((uint32_t)__half_as_ushort(__float2half(v[2 * k + 1])) << 16);
    }

    uint4* dst = (uint4*)(outT + (size_t)s * NCH);
    dst[0] = make_uint4(u[0], u[1], u[2], u[3]);
    dst[1] = make_uint4(u[4], u[5], u[6], u[7]);
}

// ---------------------------------------------------------------------------
// Binning: zero -> histogram -> exclusive scan -> scatter
// ---------------------------------------------------------------------------
__global__ __launch_bounds__(256) void zero_counts_kernel(int* __restrict__ counts) {
    const int t = threadIdx.x;
#pragma unroll
    for (int k = 0; k < NBINS / 256; ++k) counts[t + 256 * k] = 0;
}

__device__ __forceinline__ int bin_of_cell(int rx, int ry, int rz) {
    const int bx = (rx & (NMESH - 1)) >> 3;
    const int by = (ry & (NMESH - 1)) >> 3;
    const int bz = (rz & (NMESH - 1)) >> 3;
    return (bx * 16 + by) * 16 + bz;
}

__global__ __launch_bounds__(256) void histogram_kernel(
    const float* __restrict__ pts, int* __restrict__ counts)
{
    const int p = blockIdx.x * 256 + threadIdx.x;
    if (p >= NPOINTS) return;
    int rx, ry, rz;
    cell_of_point(pts[p * 3 + 0], pts[p * 3 + 1], pts[p * 3 + 2], rx, ry, rz);
    atomicAdd(&counts[bin_of_cell(rx, ry, rz)], 1);
}

__global__ __launch_bounds__(256) void scan_kernel(
    const int* __restrict__ counts, int* __restrict__ offsets)
{
    __shared__ int s[256];
    const int t = threadIdx.x;
    const int base = t * (NBINS / 256);  // 16 bins per thread

    int local[NBINS / 256];
    int total = 0;
#pragma unroll
    for (int i = 0; i < NBINS / 256; ++i) {
        local[i] = counts[base + i];
        total += local[i];
    }
    s[t] = total;
    __syncthreads();

    // Hillis-Steele inclusive scan over 256 partials
    for (int off = 1; off < 256; off <<= 1) {
        int v = (t >= off) ? s[t - off] : 0;
        __syncthreads();
        s[t] += v;
        __syncthreads();
    }
    int running = s[t] - total;  // exclusive prefix for this thread's chunk
#pragma unroll
    for (int i = 0; i < NBINS / 256; ++i) {
        offsets[base + i] = running;
        running += local[i];
    }
}

__global__ __launch_bounds__(256) void scatter_kernel(
    const float* __restrict__ pts, int* __restrict__ offsets,
    float4* __restrict__ sorted)
{
    const int p = blockIdx.x * 256 + threadIdx.x;
    if (p >= NPOINTS) return;
    const float px = pts[p * 3 + 0];
    const float py = pts[p * 3 + 1];
    const float pz = pts[p * 3 + 2];
    int rx, ry, rz;
    cell_of_point(px, py, pz, rx, ry, rz);
    const int pos = atomicAdd(&offsets[bin_of_cell(rx, ry, rz)], 1);
    sorted[pos] = make_float4(px, py, pz, __int_as_float(p));
}

// ---------------------------------------------------------------------------
// Gather from binned/sorted points. 4 lanes per point, 8 B per tap.
// Wave = 16 spatially-adjacent points -> ~32 KB footprint -> L1 hits.
// ---------------------------------------------------------------------------
__global__ __launch_bounds__(256) void gather_sorted_kernel(
    const __half* __restrict__ meshT,
    const float4* __restrict__ sorted,
    float* __restrict__ out)
{
    const int tid = blockIdx.x * 256 + threadIdx.x;
    const int si = tid >> 2;
    const int c0 = (tid & 3) * 4;
    if (si >= NPOINTS) return;

    const float4 sp = sorted[si];
    const int orig = __float_as_int(sp.w);

    const float SP = 0.1f;
    const float pcx = sp.x / SP;
    const float pcy = sp.y / SP;
    const float pcz = sp.z / SP;

    const int rx = (int)rintf(pcx);
    const int ry = (int)rintf(pcy);
    const int rz = (int)rintf(pcz);

    const float dx = pcx - (float)rx;
    const float dy = pcy - (float)ry;
    const float dz = pcz - (float)rz;

    float wX[3], wY[3], wZ[3];
    wX[0] = (2.0f * dx - 1.0f) * (2.0f * dx - 1.0f) * 0.125f;
    wX[1] = 0.75f - dx * dx;
    wX[2] = (2.0f * dx + 1.0f) * (2.0f * dx + 1.0f) * 0.125f;
    wY[0] = (2.0f * dy - 1.0f) * (2.0f * dy - 1.0f) * 0.125f;
    wY[1] = 0.75f - dy * dy;
    wY[2] = (2.0f * dy + 1.0f) * (2.0f * dy + 1.0f) * 0.125f;
    wZ[0] = (2.0f * dz - 1.0f) * (2.0f * dz - 1.0f) * 0.125f;
    wZ[1] = 0.75f - dz * dz;
    wZ[2] = (2.0f * dz + 1.0f) * (2.0f * dz + 1.0f) * 0.125f;

    int xo[3], yo[3], zo[3];
#pragma unroll
    for (int k = 0; k < 3; ++k) {
        xo[k] = ((rx - 1 + k) & (NMESH - 1)) * (NMESH2 * NCH);
        yo[k] = ((ry - 1 + k) & (NMESH - 1)) * (NMESH * NCH);
        zo[k] = ((rz - 1 + k) & (NMESH - 1)) * NCH + c0;
    }

    float acc0 = 0.0f, acc1 = 0.0f, acc2 = 0.0f, acc3 = 0.0f;
#pragma unroll
    for (int a = 0; a < 3; ++a) {
#pragma unroll
        for (int b = 0; b < 3; ++b) {
            const int base = xo[a] + yo[b];
            const float wxy = wX[a] * wY[b];
#pragma unroll
            for (int k = 0; k < 3; ++k) {
                const float2 raw = *(const float2*)(meshT + base + zo[k]);
                const __half2 h01 = *(const __half2*)&raw.x;
                const __half2 h23 = *(const __half2*)&raw.y;
                const float2 f01 = __half22float2(h01);
                const float2 f23 = __half22float2(h23);
                const float w = wxy * wZ[k];
                acc0 = fmaf(f01.x, w, acc0);
                acc1 = fmaf(f01.y, w, acc1);
                acc2 = fmaf(f23.x, w, acc2);
                acc3 = fmaf(f23.y, w, acc3);
            }
        }
    }

    *(float4*)(out + (size_t)orig * NCH + c0) = make_float4(acc0, acc1, acc2, acc3);
}

// ---------------------------------------------------------------------------
// Fallback (round-1 kernel) if ws too small.
// ---------------------------------------------------------------------------
__global__ __launch_bounds__(256) void mesh_interp_fallback_kernel(
    const float* __restrict__ mesh,
    const float* __restrict__ pts,
    float* __restrict__ out)
{
    const int tid = blockIdx.x * 256 + threadIdx.x;
    const int c = tid & (NCH - 1);
    const int p = tid >> 4;
    if (p >= NPOINTS) return;

    const float SP = 0.1f;
    const float pcx = pts[p * 3 + 0] / SP;
    const float pcy = pts[p * 3 + 1] / SP;
    const float pcz = pts[p * 3 + 2] / SP;

    const int rx = (int)rintf(pcx);
    const int ry = (int)rintf(pcy);
    const int rz = (int)rintf(pcz);

    const float dx = pcx - (float)rx;
    const float dy = pcy - (float)ry;
    const float dz = pcz - (float)rz;

    float wX[3], wY[3], wZ[3];
    wX[0] = (2.0f * dx - 1.0f) * (2.0f * dx - 1.0f) * 0.125f;
    wX[1] = 0.75f - dx * dx;
    wX[2] = (2.0f * dx + 1.0f) * (2.0f * dx + 1.0f) * 0.125f;
    wY[0] = (2.0f * dy - 1.0f) * (2.0f * dy - 1.0f) * 0.125f;
    wY[1] = 0.75f - dy * dy;
    wY[2] = (2.0f * dy + 1.0f) * (2.0f * dy + 1.0f) * 0.125f;
    wZ[0] = (2.0f * dz - 1.0f) * (2.0f * dz - 1.0f) * 0.125f;
    wZ[1] = 0.75f - dz * dz;
    wZ[2] = (2.0f * dz + 1.0f) * (2.0f * dz + 1.0f) * 0.125f;

    int xb[3], yb[3], zi[3];
#pragma unroll
    for (int k = 0; k < 3; ++k) {
        xb[k] = ((rx - 1 + k) & (NMESH - 1)) * NMESH2;
        yb[k] = ((ry - 1 + k) & (NMESH - 1)) * NMESH;
        zi[k] = ((rz - 1 + k) & (NMESH - 1));
    }

    const float* __restrict__ mc = mesh + (size_t)c * NMESH3;
    float acc = 0.0f;
#pragma unroll
    for (int a = 0; a < 3; ++a) {
#pragma unroll
        for (int b = 0; b < 3; ++b) {
            const float* __restrict__ row = mc + xb[a] + yb[b];
            const float wxy = wX[a] * wY[b];
            acc = fmaf(row[zi[0]], wxy * wZ[0], acc);
            acc = fmaf(row[zi[1]], wxy * wZ[1], acc);
            acc = fmaf(row[zi[2]], wxy * wZ[2], acc);
        }
    }
    out[tid] = acc;
}

extern "C" void kernel_launch(void* const* d_in, const int* in_sizes, int n_in,
                              void* d_out, int out_size, void* d_ws, size_t ws_size,
                              hipStream_t stream) {
    const float* mesh = (const float*)d_in[0];
    const float* pts  = (const float*)d_in[1];
    float* out        = (float*)d_out;

    if (ws_size >= WS_NEEDED) {
        char* ws = (char*)d_ws;
        __half* meshT   = (__half*)(ws + WS_MESHT_OFF);
        int*    counts  = (int*)(ws + WS_COUNTS_OFF);
        int*    offsets = (int*)(ws + WS_OFFSETS_OFF);
        float4* sorted  = (float4*)(ws + WS_SORTED_OFF);

        transpose_to_half_v2<<<NMESH3 / 256, 256, 0, stream>>>(mesh, meshT);
        zero_counts_kernel<<<1, 256, 0, stream>>>(counts);
        histogram_kernel<<<(NPOINTS + 255) / 256, 256, 0, stream>>>(pts, counts);
        scan_kernel<<<1, 256, 0, stream>>>(counts, offsets);
        scatter_kernel<<<(NPOINTS + 255) / 256, 256, 0, stream>>>(pts, offsets, sorted);
        gather_sorted_kernel<<<(NPOINTS * 4 + 255) / 256, 256, 0, stream>>>(meshT, sorted, out);
    } else {
        mesh_interp_fallback_kernel<<<(NPOINTS * NCH + 255) / 256, 256, 0, stream>>>(mesh, pts, out);
    }
}